// Round 23
// baseline (216.500 us; speedup 1.0000x reference)
//
#include <hip/hip_runtime.h>
#include <math.h>

typedef _Float16 v8h __attribute__((ext_vector_type(8)));
typedef __fp16 h2 __attribute__((ext_vector_type(2)));
typedef float v4f __attribute__((ext_vector_type(4)));
typedef float v16f __attribute__((ext_vector_type(16)));

#define MFMA32(a, b, c) __builtin_amdgcn_mfma_f32_32x32x16_f16((a), (b), (c), 0, 0, 0)
#define MFMA16(a, b, c) __builtin_amdgcn_mfma_f32_16x16x32_f16((a), (b), (c), 0, 0, 0)
#define ZV4 ((v4f){0.f, 0.f, 0.f, 0.f})
#define LOG2E 1.44269504f

// swizzled tile addressing (byte offsets)
#define TA64(row, colb)  ((((row) * 128) + (colb)) ^ (((row) & 7) << 4))
#define TA128(row, colb) ((((row) * 256) + (colb)) ^ (((row) & 15) << 4))

// raw barrier: LDS writes visible; global loads STAY IN FLIGHT (no vmcnt drain)
#define RAW_BARRIER() do {                                        \
    asm volatile("s_waitcnt lgkmcnt(0)" ::: "memory");            \
    asm volatile("s_barrier" ::: "memory");                       \
} while (0)

__device__ __forceinline__ unsigned int pk_f16(float a, float b) {
    return __builtin_bit_cast(unsigned int, __builtin_amdgcn_cvt_pkrtz(a, b));
}
__device__ __forceinline__ void pl32swap(unsigned int& a, unsigned int& b) {
    asm("v_permlane32_swap_b32 %0, %1" : "+v"(a), "+v"(b));
}
__device__ __forceinline__ float fexp2(float x) {   // bare v_exp_f32 (2^x)
    float r;
    asm("v_exp_f32 %0, %1" : "=v"(r) : "v"(x));
    return r;
}

// ---------------------------------------------------------------- k_prep ----
__global__ __launch_bounds__(256) void k_prep(
    const float* __restrict__ tw, const float* __restrict__ pw,
    const float* __restrict__ gw,
    const float* __restrict__ Ww, const float* __restrict__ Wb,
    const float* __restrict__ gamma, const float* __restrict__ beta,
    const float* __restrict__ mean, const float* __restrict__ var,
    _Float16* __restrict__ Wt, _Float16* __restrict__ wallT,
    float* __restrict__ sc, float* __restrict__ bi)
{
    int gid = blockIdx.x * 256 + threadIdx.x;    // 4096 threads
    #pragma unroll
    for (int r = 0; r < 2; ++r) {
        int idx = r * 4096 + gid;                // 8192 = 64*128
        int d = idx >> 7, c = idx & 127;
        Wt[c * 64 + d] = (_Float16)Ww[idx];      // Wt[c][d] = W_w[d][c]
    }
    #pragma unroll
    for (int r = 0; r < 6; ++r) {
        int idx = r * 4096 + gid;                // 24576 = 3*64*128
        int p = idx >> 13, rem = idx & 8191;
        int o = rem >> 7, k = rem & 127;
        const float* wm = (p == 0) ? tw : (p == 1) ? pw : gw;
        wallT[idx] = (_Float16)wm[k * 64 + o];
    }
    if (blockIdx.x == 0 && threadIdx.x < 128) {
        int c = threadIdx.x;
        float inv = gamma[c] * rsqrtf(var[c] + 1e-4f);
        sc[c] = inv;
        bi[c] = (Wb[c] - mean[c]) * inv + beta[c];
    }
}

// ---------------------------------------------------------------- k_proj ----
// fp16 MFMA projections. theta PRE-SCALED by log2(e). theta/phi via per-wave
// LDS transpose (coalesced); g via BLOCK LDS transpose -> 256B coalesced rows.
__global__ __launch_bounds__(512, 4) void k_proj(
    const float* __restrict__ x, const _Float16* __restrict__ wallT,
    const float* __restrict__ tb, const float* __restrict__ pb,
    const float* __restrict__ gb,
    _Float16* __restrict__ theta, _Float16* __restrict__ phi,
    _Float16* __restrict__ gT)
{
    __shared__ __align__(16) _Float16 tsc[8][16 * 72];   // 18KB per-wave
    __shared__ __align__(16) _Float16 gblk[64][136];     // 17KB block g tile
    const int t = threadIdx.x;
    const int w = t >> 6, l = t & 63, h = l >> 4, lo = l & 15;
    const int tok0 = blockIdx.x * 128 + w * 16;
    _Float16* tw_l = &tsc[w][0];

    v8h xA[4];
    #pragma unroll
    for (int kc = 0; kc < 4; ++kc) {
        const float* px = x + (size_t)(tok0 + lo) * 128 + kc * 32 + h * 8;
        float4 f0 = *(const float4*)(px);
        float4 f1 = *(const float4*)(px + 4);
        uint4 u;
        u.x = pk_f16(f0.x, f0.y); u.y = pk_f16(f0.z, f0.w);
        u.z = pk_f16(f1.x, f1.y); u.w = pk_f16(f1.z, f1.w);
        xA[kc] = __builtin_bit_cast(v8h, u);
    }

    #pragma unroll
    for (int p = 0; p < 2; ++p) {                // theta, phi
        const _Float16* wp = wallT + p * 8192;
        const float* bias = (p == 0) ? tb : pb;
        _Float16* dst = (p == 0) ? theta : phi;
        const float scale = (p == 0) ? LOG2E : 1.0f;
        #pragma unroll
        for (int oc = 0; oc < 4; ++oc) {
            int o = oc * 16 + lo;
            v4f acc = ZV4;
            #pragma unroll
            for (int kc = 0; kc < 4; ++kc) {
                v8h B = *(const v8h*)(wp + o * 128 + kc * 32 + h * 8);
                acc = MFMA16(xA[kc], B, acc);
            }
            float bv = bias[o];
            #pragma unroll
            for (int rr = 0; rr < 4; ++rr)
                tw_l[(4 * h + rr) * 72 + o] = (_Float16)((acc[rr] + bv) * scale);
        }
        int token = l >> 2, c = l & 3;
        v8h v0 = *(const v8h*)&tw_l[token * 72 + c * 16];
        v8h v1 = *(const v8h*)&tw_l[token * 72 + c * 16 + 8];
        _Float16* dp = dst + (size_t)(tok0 + token) * 64 + c * 16;
        *(v8h*)(dp) = v0;
        *(v8h*)(dp + 8) = v1;
    }
    // g: swapped MFMA -> D[o][token] -> block LDS -> coalesced 256B stores
    {
        const _Float16* wp = wallT + 2 * 8192;
        #pragma unroll
        for (int oc = 0; oc < 4; ++oc) {
            v4f acc = ZV4;
            #pragma unroll
            for (int kc = 0; kc < 4; ++kc) {
                v8h A = *(const v8h*)(wp + (oc * 16 + lo) * 128 + kc * 32 + h * 8);
                acc = MFMA16(A, xA[kc], acc);
            }
            #pragma unroll
            for (int rr = 0; rr < 4; ++rr) {
                int o = oc * 16 + 4 * h + rr;
                gblk[o][w * 16 + lo] = (_Float16)(acc[rr] + gb[o]);
            }
        }
    }
    __syncthreads();
    {
        int o = t >> 3, ch = t & 7;
        v8h v0 = *(const v8h*)&gblk[o][ch * 16];
        v8h v1 = *(const v8h*)&gblk[o][ch * 16 + 8];
        int tokg0 = blockIdx.x * 128;
        int bb = tokg0 >> 12, n0 = (tokg0 & 4095) + ch * 16;
        _Float16* gp = gT + ((size_t)bb * 64 + o) * 4096 + n0;
        *(v8h*)(gp) = v0;
        *(v8h*)(gp + 8) = v1;
    }
}

// ---------------------------------------------------------------- k_attn ----
// r19 loop re-partitioned for TLP: 256-thread blocks (4 waves = 4 kh), 64 q
// per block (64 q/wave via 2 f-sets), grid 512 -> multiple blocks/CU so
// block-private barriers stall only 1/4 of the CU. SINGLE-buffered ph+gv
// (32KB) with two RAW barriers/iter: compute -> issue loads -> barrier ->
// write -> barrier. In-register P, log2 softmax, defer-max, XCD partition.
__global__ __launch_bounds__(256, 4) void k_attn(
    const _Float16* __restrict__ theta,
    const _Float16* __restrict__ phi,
    const _Float16* __restrict__ gT,
    const _Float16* __restrict__ Wt,
    const float* __restrict__ sc, const float* __restrict__ bi,
    const float* __restrict__ x, float* __restrict__ out)
{
    __shared__ __align__(16) _Float16 ldsbuf[16384];     // 32KB: ph | gv
    __shared__ float zf[4 * 64];                         // 1KB: m + log2 l

    const int t = threadIdx.x;
    const int w = t >> 6, l = t & 63, q32 = l & 31, hi2 = l >> 5;
    const int kh = w;                            // wave = key quarter
    const int bid = blockIdx.x;
    const int b = bid & 7, qb = bid >> 3;        // qb 0..63 (64 q each)
    const size_t tok0 = (size_t)b * 4096 + qb * 64;

    char* phC = (char*)ldsbuf;                           // 16KB, TA64
    char* gvC = (char*)ldsbuf + 16384;                   // 16KB, TA128

    // theta B-frags (log2-scaled): q = f*32 + q32
    v8h thB[2][4];
    #pragma unroll
    for (int f = 0; f < 2; ++f)
        #pragma unroll
        for (int kc = 0; kc < 4; ++kc)
            thB[f][kc] = *(const v8h*)(theta +
                (tok0 + f * 32 + q32) * 64 + kc * 16 + hi2 * 8);

    const _Float16* phb = phi + (size_t)b * 4096 * 64;
    const _Float16* gvb = gT + (size_t)b * 64 * 4096;

    v16f yacc[2][2];                     // [f][df]
    #pragma unroll
    for (int f = 0; f < 2; ++f)
        #pragma unroll
        for (int df = 0; df < 2; ++df)
            #pragma unroll
            for (int r = 0; r < 16; ++r) yacc[f][df][r] = 0.f;
    float mrow[2] = {-INFINITY, -INFINITY}, lpart[2] = {0.f, 0.f};

    // hoisted swizzled read offsets
    int qkRd[4], gvRd[2][2];
    #pragma unroll
    for (int kc = 0; kc < 4; ++kc)
        qkRd[kc] = TA64(kh * 32 + q32, (kc * 16 + hi2 * 8) * 2);
    #pragma unroll
    for (int df = 0; df < 2; ++df)
        #pragma unroll
        for (int s = 0; s < 2; ++s)
            gvRd[df][s] = TA128(df * 32 + q32, (kh * 32 + s * 16 + hi2 * 8) * 2);

    // staging (256 thr, 8 chunks each): ph rows t>>3 + j*32; gv rows t>>4 + j*16
    int phA[4], gvA[4];
    #pragma unroll
    for (int j = 0; j < 4; ++j) {
        phA[j] = TA64(j * 32 + (t >> 3), (t & 7) * 16);
        gvA[j] = TA128(j * 16 + (t >> 4), (t & 15) * 16);
    }
    const _Float16* pPh = phb + (size_t)(t >> 3) * 64 + (t & 7) * 8;
    const _Float16* pGv = gvb + (size_t)(t >> 4) * 4096 + (t & 15) * 8;

    // prologue: stage tile 0
    {
        #pragma unroll
        for (int j = 0; j < 4; ++j) {
            *(v8h*)(phC + phA[j]) = *(const v8h*)(pPh + j * 2048);
            *(v8h*)(gvC + gvA[j]) = *(const v8h*)(pGv + (size_t)j * 65536);
        }
    }
    RAW_BARRIER();

    for (int kt = 0; kt < 32; ++kt) {
        // ---- QK^T (log2): both q-sets issued together
        v16f S0, S1;
        #pragma unroll
        for (int r = 0; r < 16; ++r) { S0[r] = 0.f; S1[r] = 0.f; }
        __builtin_amdgcn_s_setprio(1);
        #pragma unroll
        for (int kc = 0; kc < 4; ++kc) {
            v8h A = *(const v8h*)(phC + qkRd[kc]);
            S0 = MFMA32(A, thB[0][kc], S0);
            S1 = MFMA32(A, thB[1][kc], S1);
        }
        __builtin_amdgcn_s_setprio(0);
        // ---- gv A-frags early; feed both PVs
        v8h gA[2][2];
        #pragma unroll
        for (int df = 0; df < 2; ++df)
            #pragma unroll
            for (int s = 0; s < 2; ++s)
                gA[df][s] = *(const v8h*)(gvC + gvRd[df][s]);
        // ---- vmax both sets + joint defer-max (THR = 8 ln-units)
        float vmax[2];
        {
            float a0 = fmaxf(fmaxf(S0[0], S0[1]), S0[2]);
            float a1 = fmaxf(fmaxf(S0[3], S0[4]), S0[5]);
            float a2 = fmaxf(fmaxf(S0[6], S0[7]), S0[8]);
            float a3 = fmaxf(fmaxf(S0[9], S0[10]), S0[11]);
            float a4 = fmaxf(fmaxf(S0[12], S0[13]), S0[14]);
            float v = fmaxf(fmaxf(fmaxf(a0, a1), fmaxf(a2, a3)),
                            fmaxf(a4, S0[15]));
            vmax[0] = fmaxf(v, __shfl_xor(v, 32));
        }
        {
            float a0 = fmaxf(fmaxf(S1[0], S1[1]), S1[2]);
            float a1 = fmaxf(fmaxf(S1[3], S1[4]), S1[5]);
            float a2 = fmaxf(fmaxf(S1[6], S1[7]), S1[8]);
            float a3 = fmaxf(fmaxf(S1[9], S1[10]), S1[11]);
            float a4 = fmaxf(fmaxf(S1[12], S1[13]), S1[14]);
            float v = fmaxf(fmaxf(fmaxf(a0, a1), fmaxf(a2, a3)),
                            fmaxf(a4, S1[15]));
            vmax[1] = fmaxf(v, __shfl_xor(v, 32));
        }
        bool ok = (vmax[0] <= mrow[0] + 11.54f) && (vmax[1] <= mrow[1] + 11.54f);
        if (!__all(ok)) {
            #pragma unroll
            for (int f = 0; f < 2; ++f) {
                float mn = fmaxf(mrow[f], vmax[f]);
                float aa = fexp2(mrow[f] - mn);          // 0 on first tile
                mrow[f] = mn;
                lpart[f] *= aa;
                #pragma unroll
                for (int df = 0; df < 2; ++df)
                    #pragma unroll
                    for (int r = 0; r < 16; ++r)
                        yacc[f][df][r] *= aa;
            }
        }
        const h2 one2 = {(__fp16)1.0f, (__fp16)1.0f};
        // ---- pipelined: softmax(f0) -> PV(f0) -> softmax(f1) -> PV(f1)
        {
            #pragma unroll
            for (int r = 0; r < 16; ++r) S0[r] = fexp2(S0[r] - mrow[0]);
            float psum = 0.f;
            h2 pk[8];
            #pragma unroll
            for (int j = 0; j < 8; ++j) {
                pk[j] = __builtin_amdgcn_cvt_pkrtz(S0[2 * j], S0[2 * j + 1]);
                psum = __builtin_amdgcn_fdot2(pk[j], one2, psum, false);
            }
            lpart[0] += psum;
            unsigned int W0 = __builtin_bit_cast(unsigned int, pk[0]);
            unsigned int W1 = __builtin_bit_cast(unsigned int, pk[1]);
            unsigned int W2 = __builtin_bit_cast(unsigned int, pk[2]);
            unsigned int W3 = __builtin_bit_cast(unsigned int, pk[3]);
            unsigned int W4 = __builtin_bit_cast(unsigned int, pk[4]);
            unsigned int W5 = __builtin_bit_cast(unsigned int, pk[5]);
            unsigned int W6 = __builtin_bit_cast(unsigned int, pk[6]);
            unsigned int W7 = __builtin_bit_cast(unsigned int, pk[7]);
            pl32swap(W0, W2); pl32swap(W1, W3);
            pl32swap(W4, W6); pl32swap(W5, W7);
            uint4 u1; u1.x = W0; u1.y = W1; u1.z = W2; u1.w = W3;
            uint4 u2; u2.x = W4; u2.y = W5; u2.z = W6; u2.w = W7;
            v8h pB0 = __builtin_bit_cast(v8h, u1);
            v8h pB1 = __builtin_bit_cast(v8h, u2);
            __builtin_amdgcn_s_setprio(1);
            yacc[0][0] = MFMA32(gA[0][0], pB0, yacc[0][0]);
            yacc[0][0] = MFMA32(gA[0][1], pB1, yacc[0][0]);
            yacc[0][1] = MFMA32(gA[1][0], pB0, yacc[0][1]);
            yacc[0][1] = MFMA32(gA[1][1], pB1, yacc[0][1]);
            __builtin_amdgcn_s_setprio(0);
        }
        {
            #pragma unroll
            for (int r = 0; r < 16; ++r) S1[r] = fexp2(S1[r] - mrow[1]);
            float psum = 0.f;
            h2 pk[8];
            #pragma unroll
            for (int j = 0; j < 8; ++j) {
                pk[j] = __builtin_amdgcn_cvt_pkrtz(S1[2 * j], S1[2 * j + 1]);
                psum = __builtin_amdgcn_fdot2(pk[j], one2, psum, false);
            }
            lpart[1] += psum;
            unsigned int W0 = __builtin_bit_cast(unsigned int, pk[0]);
            unsigned int W1 = __builtin_bit_cast(unsigned int, pk[1]);
            unsigned int W2 = __builtin_bit_cast(unsigned int, pk[2]);
            unsigned int W3 = __builtin_bit_cast(unsigned int, pk[3]);
            unsigned int W4 = __builtin_bit_cast(unsigned int, pk[4]);
            unsigned int W5 = __builtin_bit_cast(unsigned int, pk[5]);
            unsigned int W6 = __builtin_bit_cast(unsigned int, pk[6]);
            unsigned int W7 = __builtin_bit_cast(unsigned int, pk[7]);
            pl32swap(W0, W2); pl32swap(W1, W3);
            pl32swap(W4, W6); pl32swap(W5, W7);
            uint4 u1; u1.x = W0; u1.y = W1; u1.z = W2; u1.w = W3;
            uint4 u2; u2.x = W4; u2.y = W5; u2.z = W6; u2.w = W7;
            v8h pB0 = __builtin_bit_cast(v8h, u1);
            v8h pB1 = __builtin_bit_cast(v8h, u2);
            __builtin_amdgcn_s_setprio(1);
            yacc[1][0] = MFMA32(gA[0][0], pB0, yacc[1][0]);
            yacc[1][0] = MFMA32(gA[0][1], pB1, yacc[1][0]);
            yacc[1][1] = MFMA32(gA[1][0], pB0, yacc[1][1]);
            yacc[1][1] = MFMA32(gA[1][1], pB1, yacc[1][1]);
            __builtin_amdgcn_s_setprio(0);
        }
        // ---- issue loads for tile kt+1 (in flight across the barrier)
        v8h np0, np1, np2, np3, ng0, ng1, ng2, ng3;
        if (kt < 31) {
            const _Float16* pp = pPh + (size_t)(kt + 1) * 8192;
            np0 = *(const v8h*)(pp);
            np1 = *(const v8h*)(pp + 2048);
            np2 = *(const v8h*)(pp + 4096);
            np3 = *(const v8h*)(pp + 6144);
            const _Float16* pg = pGv + (size_t)(kt + 1) * 128;
            ng0 = *(const v8h*)(pg);
            ng1 = *(const v8h*)(pg + 65536);
            ng2 = *(const v8h*)(pg + 131072);
            ng3 = *(const v8h*)(pg + 196608);
        }
        RAW_BARRIER();                   // all reads of tile kt done
        if (kt < 31) {                   // write tile kt+1 (counted vmcnt)
            *(v8h*)(phC + phA[0]) = np0;
            *(v8h*)(phC + phA[1]) = np1;
            *(v8h*)(phC + phA[2]) = np2;
            *(v8h*)(phC + phA[3]) = np3;
            *(v8h*)(gvC + gvA[0]) = ng0;
            *(v8h*)(gvC + gvA[1]) = ng1;
            *(v8h*)(gvC + gvA[2]) = ng2;
            *(v8h*)(gvC + gvA[3]) = ng3;
        }
        RAW_BARRIER();                   // tile kt+1 visible
    }

    // ---- write partials: u = y/l (fp16); slot w = 8KB (4KB per f)
    #pragma unroll
    for (int f = 0; f < 2; ++f) {
        float lrow = lpart[f] + __shfl_xor(lpart[f], 32);
        float inv = 1.0f / lrow;
        char* slot = (char*)ldsbuf + w * 8192 + f * 4096 + l * 64;
        #pragma unroll
        for (int j = 0; j < 4; ++j) {
            int df = j >> 1, r0 = (j & 1) * 8;
            uint4 u;
            u.x = pk_f16(yacc[f][df][r0 + 0] * inv, yacc[f][df][r0 + 1] * inv);
            u.y = pk_f16(yacc[f][df][r0 + 2] * inv, yacc[f][df][r0 + 3] * inv);
            u.z = pk_f16(yacc[f][df][r0 + 4] * inv, yacc[f][df][r0 + 5] * inv);
            u.w = pk_f16(yacc[f][df][r0 + 6] * inv, yacc[f][df][r0 + 7] * inv);
            *(uint4*)(slot + (j * 16 ^ ((l & 3) << 4))) = u;
        }
        zf[(w * 2 + f) * 32 + q32] = mrow[f] + __log2f(lrow);
    }
    __syncthreads();
    if (w >= 2) return;

    // ---- combine 4 kh partials; wave w handles f-set f = w
    {
        const int f = w;
        float zq[4];
        #pragma unroll
        for (int kp = 0; kp < 4; ++kp)
            zq[kp] = zf[(kp * 2 + f) * 32 + q32];
        float zmx = fmaxf(fmaxf(zq[0], zq[1]), fmaxf(zq[2], zq[3]));
        float wsum = 0.f;
        float yfin[2][16];
        #pragma unroll
        for (int df = 0; df < 2; ++df)
            #pragma unroll
            for (int r = 0; r < 16; ++r) yfin[df][r] = 0.f;
        #pragma unroll
        for (int kp = 0; kp < 4; ++kp) {
            char* slot = (char*)ldsbuf + kp * 8192 + f * 4096 + l * 64;
            float wk = fexp2(zq[kp] - zmx);
            wsum += wk;
            #pragma unroll
            for (int j = 0; j < 4; ++j) {
                v8h c = *(const v8h*)(slot + (j * 16 ^ ((l & 3) << 4)));
                int df = j >> 1, r0 = (j & 1) * 8;
                #pragma unroll
                for (int e = 0; e < 8; ++e)
                    yfin[df][r0 + e] += wk * (float)c[e];
            }
        }
        float nrm = 1.0f / wsum;
        // epilogue A-frags: y rows q, k = d
        v8h yA[4];
        #pragma unroll
        for (int kc = 0; kc < 4; ++kc) {
            int df = kc >> 1, r0 = (kc & 1) * 8;
            unsigned int Wa = pk_f16(yfin[df][r0 + 0] * nrm, yfin[df][r0 + 1] * nrm);
            unsigned int Wb2 = pk_f16(yfin[df][r0 + 2] * nrm, yfin[df][r0 + 3] * nrm);
            unsigned int Wc = pk_f16(yfin[df][r0 + 4] * nrm, yfin[df][r0 + 5] * nrm);
            unsigned int Wd = pk_f16(yfin[df][r0 + 6] * nrm, yfin[df][r0 + 7] * nrm);
            pl32swap(Wa, Wc); pl32swap(Wb2, Wd);
            uint4 u; u.x = Wa; u.y = Wb2; u.z = Wc; u.w = Wd;
            yA[kc] = __builtin_bit_cast(v8h, u);
        }
        // wy = y @ W -> BN + residual; queries qb*64 + f*32 + qrow
        const int tokA = qb * 64 + f * 32;
        const float* xb = x + (size_t)b * 4096 * 128;
        float* ob = out + (size_t)b * 4096 * 128;
        #pragma unroll
        for (int cf = 0; cf < 4; ++cf) {
            int c = cf * 32 + q32;
            v16f wy;
            #pragma unroll
            for (int r = 0; r < 16; ++r) wy[r] = 0.f;
            #pragma unroll
            for (int kc = 0; kc < 4; ++kc) {
                v8h wB = *(const v8h*)(Wt + c * 64 + kc * 16 + hi2 * 8);
                wy = MFMA32(yA[kc], wB, wy);
            }
            float scc = sc[c], bic = bi[c];
            #pragma unroll
            for (int r = 0; r < 16; ++r) {
                int qrow = (r & 3) + 8 * (r >> 2) + 4 * hi2;
                size_t off = (size_t)(tokA + qrow) * 128 + c;
                ob[off] = wy[r] * scc + bic + xb[off];
            }
        }
    }
}

// ------------------------------------------------------------------ launch --
extern "C" void kernel_launch(void* const* d_in, const int* in_sizes, int n_in,
                              void* d_out, int out_size, void* d_ws, size_t ws_size,
                              hipStream_t stream) {
    const float* x     = (const float*)d_in[0];
    const float* tw    = (const float*)d_in[1];
    const float* tb    = (const float*)d_in[2];
    const float* pw    = (const float*)d_in[3];
    const float* pb    = (const float*)d_in[4];
    const float* gw    = (const float*)d_in[5];
    const float* gb    = (const float*)d_in[6];
    const float* Ww    = (const float*)d_in[7];
    const float* Wb    = (const float*)d_in[8];
    const float* gamma = (const float*)d_in[9];
    const float* beta  = (const float*)d_in[10];
    const float* mean  = (const float*)d_in[11];
    const float* var   = (const float*)d_in[12];

    char* ws = (char*)d_ws;
    _Float16* theta = (_Float16*)ws;                       // 4 MB (log2-scaled)
    _Float16* phi   = (_Float16*)(ws + (4u << 20));        // 4 MB
    _Float16* gT    = (_Float16*)(ws + (8u << 20));        // 4 MB
    _Float16* Wt    = (_Float16*)(ws + (12u << 20));       // 16 KB
    _Float16* wallT = (_Float16*)(ws + (12u << 20) + (1u << 16));  // 48 KB
    float* sc       = (float*)(ws + (12u << 20) + (2u << 16));
    float* bi       = sc + 128;

    k_prep<<<16, 256, 0, stream>>>(tw, pw, gw, Ww, Wb, gamma, beta, mean, var,
                                   Wt, wallT, sc, bi);
    k_proj<<<256, 512, 0, stream>>>(x, wallT, tb, pb, gb, theta, phi, gT);
    k_attn<<<512, 256, 0, stream>>>(theta, phi, gT, Wt, sc, bi,
                                    x, (float*)d_out);
}

// Round 24
// 82.227 us; speedup vs baseline: 2.6329x; 2.6329x over previous
//
#include <hip/hip_runtime.h>
#include <math.h>

typedef _Float16 v8h __attribute__((ext_vector_type(8)));
typedef __fp16 h2 __attribute__((ext_vector_type(2)));
typedef float v4f __attribute__((ext_vector_type(4)));
typedef float v16f __attribute__((ext_vector_type(16)));

#define MFMA32(a, b, c) __builtin_amdgcn_mfma_f32_32x32x16_f16((a), (b), (c), 0, 0, 0)
#define MFMA16(a, b, c) __builtin_amdgcn_mfma_f32_16x16x32_f16((a), (b), (c), 0, 0, 0)
#define ZV4 ((v4f){0.f, 0.f, 0.f, 0.f})
#define LOG2E 1.44269504f

// swizzled tile addressing (byte offsets)
#define TA64(row, colb)  ((((row) * 128) + (colb)) ^ (((row) & 7) << 4))
#define TA128(row, colb) ((((row) * 256) + (colb)) ^ (((row) & 15) << 4))

// raw barrier: LDS writes visible; global loads STAY IN FLIGHT (no vmcnt drain)
#define RAW_BARRIER() do {                                        \
    asm volatile("s_waitcnt lgkmcnt(0)" ::: "memory");            \
    asm volatile("s_barrier" ::: "memory");                       \
} while (0)

__device__ __forceinline__ unsigned int pk_f16(float a, float b) {
    return __builtin_bit_cast(unsigned int, __builtin_amdgcn_cvt_pkrtz(a, b));
}
__device__ __forceinline__ void pl32swap(unsigned int& a, unsigned int& b) {
    asm("v_permlane32_swap_b32 %0, %1" : "+v"(a), "+v"(b));
}
__device__ __forceinline__ float fexp2(float x) {   // bare v_exp_f32 (2^x)
    float r;
    asm("v_exp_f32 %0, %1" : "=v"(r) : "v"(x));
    return r;
}

// ---------------------------------------------------------------- k_prep ----
__global__ __launch_bounds__(256) void k_prep(
    const float* __restrict__ tw, const float* __restrict__ pw,
    const float* __restrict__ gw,
    const float* __restrict__ Ww, const float* __restrict__ Wb,
    const float* __restrict__ gamma, const float* __restrict__ beta,
    const float* __restrict__ mean, const float* __restrict__ var,
    _Float16* __restrict__ Wt, _Float16* __restrict__ wallT,
    float* __restrict__ sc, float* __restrict__ bi)
{
    int gid = blockIdx.x * 256 + threadIdx.x;    // 4096 threads
    #pragma unroll
    for (int r = 0; r < 2; ++r) {
        int idx = r * 4096 + gid;                // 8192 = 64*128
        int d = idx >> 7, c = idx & 127;
        Wt[c * 64 + d] = (_Float16)Ww[idx];      // Wt[c][d] = W_w[d][c]
    }
    #pragma unroll
    for (int r = 0; r < 6; ++r) {
        int idx = r * 4096 + gid;                // 24576 = 3*64*128
        int p = idx >> 13, rem = idx & 8191;
        int o = rem >> 7, k = rem & 127;
        const float* wm = (p == 0) ? tw : (p == 1) ? pw : gw;
        wallT[idx] = (_Float16)wm[k * 64 + o];
    }
    if (blockIdx.x == 0 && threadIdx.x < 128) {
        int c = threadIdx.x;
        float inv = gamma[c] * rsqrtf(var[c] + 1e-4f);
        sc[c] = inv;
        bi[c] = (Wb[c] - mean[c]) * inv + beta[c];
    }
}

// ---------------------------------------------------------------- k_proj ----
// fp16 MFMA projections. theta PRE-SCALED by log2(e). theta/phi via per-wave
// LDS transpose (coalesced); g via BLOCK LDS transpose -> 256B coalesced rows.
__global__ __launch_bounds__(512, 4) void k_proj(
    const float* __restrict__ x, const _Float16* __restrict__ wallT,
    const float* __restrict__ tb, const float* __restrict__ pb,
    const float* __restrict__ gb,
    _Float16* __restrict__ theta, _Float16* __restrict__ phi,
    _Float16* __restrict__ gT)
{
    __shared__ __align__(16) _Float16 tsc[8][16 * 72];   // 18KB per-wave
    __shared__ __align__(16) _Float16 gblk[64][136];     // 17KB block g tile
    const int t = threadIdx.x;
    const int w = t >> 6, l = t & 63, h = l >> 4, lo = l & 15;
    const int tok0 = blockIdx.x * 128 + w * 16;
    _Float16* tw_l = &tsc[w][0];

    v8h xA[4];
    #pragma unroll
    for (int kc = 0; kc < 4; ++kc) {
        const float* px = x + (size_t)(tok0 + lo) * 128 + kc * 32 + h * 8;
        float4 f0 = *(const float4*)(px);
        float4 f1 = *(const float4*)(px + 4);
        uint4 u;
        u.x = pk_f16(f0.x, f0.y); u.y = pk_f16(f0.z, f0.w);
        u.z = pk_f16(f1.x, f1.y); u.w = pk_f16(f1.z, f1.w);
        xA[kc] = __builtin_bit_cast(v8h, u);
    }

    #pragma unroll
    for (int p = 0; p < 2; ++p) {                // theta, phi
        const _Float16* wp = wallT + p * 8192;
        const float* bias = (p == 0) ? tb : pb;
        _Float16* dst = (p == 0) ? theta : phi;
        const float scale = (p == 0) ? LOG2E : 1.0f;
        #pragma unroll
        for (int oc = 0; oc < 4; ++oc) {
            int o = oc * 16 + lo;
            v4f acc = ZV4;
            #pragma unroll
            for (int kc = 0; kc < 4; ++kc) {
                v8h B = *(const v8h*)(wp + o * 128 + kc * 32 + h * 8);
                acc = MFMA16(xA[kc], B, acc);
            }
            float bv = bias[o];
            #pragma unroll
            for (int rr = 0; rr < 4; ++rr)
                tw_l[(4 * h + rr) * 72 + o] = (_Float16)((acc[rr] + bv) * scale);
        }
        int token = l >> 2, c = l & 3;
        v8h v0 = *(const v8h*)&tw_l[token * 72 + c * 16];
        v8h v1 = *(const v8h*)&tw_l[token * 72 + c * 16 + 8];
        _Float16* dp = dst + (size_t)(tok0 + token) * 64 + c * 16;
        *(v8h*)(dp) = v0;
        *(v8h*)(dp + 8) = v1;
    }
    // g: swapped MFMA -> D[o][token] -> block LDS -> coalesced 256B stores
    {
        const _Float16* wp = wallT + 2 * 8192;
        #pragma unroll
        for (int oc = 0; oc < 4; ++oc) {
            v4f acc = ZV4;
            #pragma unroll
            for (int kc = 0; kc < 4; ++kc) {
                v8h A = *(const v8h*)(wp + (oc * 16 + lo) * 128 + kc * 32 + h * 8);
                acc = MFMA16(A, xA[kc], acc);
            }
            #pragma unroll
            for (int rr = 0; rr < 4; ++rr) {
                int o = oc * 16 + 4 * h + rr;
                gblk[o][w * 16 + lo] = (_Float16)(acc[rr] + gb[o]);
            }
        }
    }
    __syncthreads();
    {
        int o = t >> 3, ch = t & 7;
        v8h v0 = *(const v8h*)&gblk[o][ch * 16];
        v8h v1 = *(const v8h*)&gblk[o][ch * 16 + 8];
        int tokg0 = blockIdx.x * 128;
        int bb = tokg0 >> 12, n0 = (tokg0 & 4095) + ch * 16;
        _Float16* gp = gT + ((size_t)bb * 64 + o) * 4096 + n0;
        *(v8h*)(gp) = v0;
        *(v8h*)(gp + 8) = v1;
    }
}

// ---------------------------------------------------------------- k_attn ----
// BEST PROVEN (r19/r22): register-blocked 64 q/wave (2 q-sets share every LDS
// A-frag), double-buffered ph+gv, ONE RAW barrier/iter (loads in flight),
// in-register P (permlane32_swap), log2 softmax (v_exp_f32), defer-max,
// intra-iter f-pipelining. Block = 128 q, 8 waves = 2 qp x 4 kh; grid 256
// (b = bid&7 XCD-partition).
__global__ __launch_bounds__(512, 2) void k_attn(
    const _Float16* __restrict__ theta,
    const _Float16* __restrict__ phi,
    const _Float16* __restrict__ gT,
    const _Float16* __restrict__ Wt,
    const float* __restrict__ sc, const float* __restrict__ bi,
    const float* __restrict__ x, float* __restrict__ out)
{
    __shared__ __align__(16) _Float16 ldsbuf[32768];     // 64KB: ph[2] | gv[2]
    __shared__ float zf[8 * 64];                         // 2KB: m + log2 l

    const int t = threadIdx.x;
    const int w = t >> 6, l = t & 63, q32 = l & 31, hi2 = l >> 5;
    const int qp = w & 1, kh = w >> 1;
    const int bid = blockIdx.x;
    const int b = bid & 7, qb = bid >> 3;        // qb 0..31 (128 q each)
    const size_t tok0 = (size_t)b * 4096 + qb * 128;

    char* phB = (char*)ldsbuf;                           // 2 x 16KB, TA64
    char* gvB = (char*)ldsbuf + 32768;                   // 2 x 16KB, TA128

    // theta B-frags (log2-scaled): q = qp*64 + f*32 + q32
    v8h thB[2][4];
    #pragma unroll
    for (int f = 0; f < 2; ++f)
        #pragma unroll
        for (int kc = 0; kc < 4; ++kc)
            thB[f][kc] = *(const v8h*)(theta +
                (tok0 + qp * 64 + f * 32 + q32) * 64 + kc * 16 + hi2 * 8);

    const _Float16* phb = phi + (size_t)b * 4096 * 64;
    const _Float16* gvb = gT + (size_t)b * 64 * 4096;

    v16f yacc[2][2];                     // [f][df]
    #pragma unroll
    for (int f = 0; f < 2; ++f)
        #pragma unroll
        for (int df = 0; df < 2; ++df)
            #pragma unroll
            for (int r = 0; r < 16; ++r) yacc[f][df][r] = 0.f;
    float mrow[2] = {-INFINITY, -INFINITY}, lpart[2] = {0.f, 0.f};

    // hoisted swizzled read offsets (within one 16KB buffer)
    int qkRd[4], gvRd[2][2];
    #pragma unroll
    for (int kc = 0; kc < 4; ++kc)
        qkRd[kc] = TA64(kh * 32 + q32, (kc * 16 + hi2 * 8) * 2);
    #pragma unroll
    for (int df = 0; df < 2; ++df)
        #pragma unroll
        for (int s = 0; s < 2; ++s)
            gvRd[df][s] = TA128(df * 32 + q32, (kh * 32 + s * 16 + hi2 * 8) * 2);

    // staging: ph 2 chunks/thread (rows t>>3, +64), gv 2 (rows t>>4, +32)
    const int phA0 = TA64(t >> 3, (t & 7) * 16);
    const int phA1 = TA64((t >> 3) + 64, (t & 7) * 16);
    const int gvA0 = TA128(t >> 4, (t & 15) * 16);
    const int gvA1 = TA128((t >> 4) + 32, (t & 15) * 16);
    const _Float16* pPh = phb + (size_t)(t >> 3) * 64 + (t & 7) * 8;
    const _Float16* pGv = gvb + (size_t)(t >> 4) * 4096 + (t & 15) * 8;

    // prefetch tile 0
    v8h pf0 = *(const v8h*)(pPh);
    v8h pf1 = *(const v8h*)(pPh + 64 * 64);
    v8h pf2 = *(const v8h*)(pGv);
    v8h pf3 = *(const v8h*)(pGv + (size_t)32 * 4096);
    pPh += 8192; pGv += 128;

    for (int kt = 0; kt < 32; ++kt) {
        char* phL = phB + (kt & 1) * 16384;
        char* gvL = gvB + (kt & 1) * 16384;
        *(v8h*)(phL + phA0) = pf0;
        *(v8h*)(phL + phA1) = pf1;
        *(v8h*)(gvL + gvA0) = pf2;
        *(v8h*)(gvL + gvA1) = pf3;
        if (kt < 31) {                   // issue loads for tile kt+1; they
            pf0 = *(const v8h*)(pPh);    // stay in flight across RAW_BARRIER
            pf1 = *(const v8h*)(pPh + 64 * 64);
            pf2 = *(const v8h*)(pGv);
            pf3 = *(const v8h*)(pGv + (size_t)32 * 4096);
            pPh += 8192; pGv += 128;
        }
        RAW_BARRIER();                   // LDS writes visible; vmem NOT drained
        // ---- QK^T (log2): both q-sets issued together
        v16f S0, S1;
        #pragma unroll
        for (int r = 0; r < 16; ++r) { S0[r] = 0.f; S1[r] = 0.f; }
        __builtin_amdgcn_s_setprio(1);
        #pragma unroll
        for (int kc = 0; kc < 4; ++kc) {
            v8h A = *(const v8h*)(phL + qkRd[kc]);
            S0 = MFMA32(A, thB[0][kc], S0);
            S1 = MFMA32(A, thB[1][kc], S1);
        }
        __builtin_amdgcn_s_setprio(0);
        // ---- gv A-frags early (latency hides under QK MFMAs); feed both PVs
        v8h gA[2][2];
        #pragma unroll
        for (int df = 0; df < 2; ++df)
            #pragma unroll
            for (int s = 0; s < 2; ++s)
                gA[df][s] = *(const v8h*)(gvL + gvRd[df][s]);
        // ---- vmax both sets + joint defer-max (THR = 8 ln-units)
        float vmax[2];
        {
            float a0 = fmaxf(fmaxf(S0[0], S0[1]), S0[2]);
            float a1 = fmaxf(fmaxf(S0[3], S0[4]), S0[5]);
            float a2 = fmaxf(fmaxf(S0[6], S0[7]), S0[8]);
            float a3 = fmaxf(fmaxf(S0[9], S0[10]), S0[11]);
            float a4 = fmaxf(fmaxf(S0[12], S0[13]), S0[14]);
            float v = fmaxf(fmaxf(fmaxf(a0, a1), fmaxf(a2, a3)),
                            fmaxf(a4, S0[15]));
            vmax[0] = fmaxf(v, __shfl_xor(v, 32));
        }
        {
            float a0 = fmaxf(fmaxf(S1[0], S1[1]), S1[2]);
            float a1 = fmaxf(fmaxf(S1[3], S1[4]), S1[5]);
            float a2 = fmaxf(fmaxf(S1[6], S1[7]), S1[8]);
            float a3 = fmaxf(fmaxf(S1[9], S1[10]), S1[11]);
            float a4 = fmaxf(fmaxf(S1[12], S1[13]), S1[14]);
            float v = fmaxf(fmaxf(fmaxf(a0, a1), fmaxf(a2, a3)),
                            fmaxf(a4, S1[15]));
            vmax[1] = fmaxf(v, __shfl_xor(v, 32));
        }
        bool ok = (vmax[0] <= mrow[0] + 11.54f) && (vmax[1] <= mrow[1] + 11.54f);
        if (!__all(ok)) {
            #pragma unroll
            for (int f = 0; f < 2; ++f) {
                float mn = fmaxf(mrow[f], vmax[f]);
                float aa = fexp2(mrow[f] - mn);          // 0 on first tile
                mrow[f] = mn;
                lpart[f] *= aa;
                #pragma unroll
                for (int df = 0; df < 2; ++df)
                    #pragma unroll
                    for (int r = 0; r < 16; ++r)
                        yacc[f][df][r] *= aa;
            }
        }
        const h2 one2 = {(__fp16)1.0f, (__fp16)1.0f};
        // ---- pipelined: softmax(f0) -> PV(f0) -> softmax(f1) -> PV(f1)
        {
            #pragma unroll
            for (int r = 0; r < 16; ++r) S0[r] = fexp2(S0[r] - mrow[0]);
            float psum = 0.f;
            h2 pk[8];
            #pragma unroll
            for (int j = 0; j < 8; ++j) {
                pk[j] = __builtin_amdgcn_cvt_pkrtz(S0[2 * j], S0[2 * j + 1]);
                psum = __builtin_amdgcn_fdot2(pk[j], one2, psum, false);
            }
            lpart[0] += psum;
            unsigned int W0 = __builtin_bit_cast(unsigned int, pk[0]);
            unsigned int W1 = __builtin_bit_cast(unsigned int, pk[1]);
            unsigned int W2 = __builtin_bit_cast(unsigned int, pk[2]);
            unsigned int W3 = __builtin_bit_cast(unsigned int, pk[3]);
            unsigned int W4 = __builtin_bit_cast(unsigned int, pk[4]);
            unsigned int W5 = __builtin_bit_cast(unsigned int, pk[5]);
            unsigned int W6 = __builtin_bit_cast(unsigned int, pk[6]);
            unsigned int W7 = __builtin_bit_cast(unsigned int, pk[7]);
            pl32swap(W0, W2); pl32swap(W1, W3);
            pl32swap(W4, W6); pl32swap(W5, W7);
            uint4 u1; u1.x = W0; u1.y = W1; u1.z = W2; u1.w = W3;
            uint4 u2; u2.x = W4; u2.y = W5; u2.z = W6; u2.w = W7;
            v8h pB0 = __builtin_bit_cast(v8h, u1);
            v8h pB1 = __builtin_bit_cast(v8h, u2);
            // PV f0 (matrix pipe busy while f1 softmax runs next)
            __builtin_amdgcn_s_setprio(1);
            yacc[0][0] = MFMA32(gA[0][0], pB0, yacc[0][0]);
            yacc[0][0] = MFMA32(gA[0][1], pB1, yacc[0][0]);
            yacc[0][1] = MFMA32(gA[1][0], pB0, yacc[0][1]);
            yacc[0][1] = MFMA32(gA[1][1], pB1, yacc[0][1]);
            __builtin_amdgcn_s_setprio(0);
        }
        // softmax f1 (overlaps PV f0 in the matrix pipe)
        {
            #pragma unroll
            for (int r = 0; r < 16; ++r) S1[r] = fexp2(S1[r] - mrow[1]);
            float psum = 0.f;
            h2 pk[8];
            #pragma unroll
            for (int j = 0; j < 8; ++j) {
                pk[j] = __builtin_amdgcn_cvt_pkrtz(S1[2 * j], S1[2 * j + 1]);
                psum = __builtin_amdgcn_fdot2(pk[j], one2, psum, false);
            }
            lpart[1] += psum;
            unsigned int W0 = __builtin_bit_cast(unsigned int, pk[0]);
            unsigned int W1 = __builtin_bit_cast(unsigned int, pk[1]);
            unsigned int W2 = __builtin_bit_cast(unsigned int, pk[2]);
            unsigned int W3 = __builtin_bit_cast(unsigned int, pk[3]);
            unsigned int W4 = __builtin_bit_cast(unsigned int, pk[4]);
            unsigned int W5 = __builtin_bit_cast(unsigned int, pk[5]);
            unsigned int W6 = __builtin_bit_cast(unsigned int, pk[6]);
            unsigned int W7 = __builtin_bit_cast(unsigned int, pk[7]);
            pl32swap(W0, W2); pl32swap(W1, W3);
            pl32swap(W4, W6); pl32swap(W5, W7);
            uint4 u1; u1.x = W0; u1.y = W1; u1.z = W2; u1.w = W3;
            uint4 u2; u2.x = W4; u2.y = W5; u2.z = W6; u2.w = W7;
            v8h pB0 = __builtin_bit_cast(v8h, u1);
            v8h pB1 = __builtin_bit_cast(v8h, u2);
            __builtin_amdgcn_s_setprio(1);
            yacc[1][0] = MFMA32(gA[0][0], pB0, yacc[1][0]);
            yacc[1][0] = MFMA32(gA[0][1], pB1, yacc[1][0]);
            yacc[1][1] = MFMA32(gA[1][0], pB0, yacc[1][1]);
            yacc[1][1] = MFMA32(gA[1][1], pB1, yacc[1][1]);
            __builtin_amdgcn_s_setprio(0);
        }
    }

    __syncthreads();                     // all tile reads done; reuse ldsbuf
    // ---- write partials: u = y/l (fp16); slot w = 8KB (4KB per f)
    #pragma unroll
    for (int f = 0; f < 2; ++f) {
        float lrow = lpart[f] + __shfl_xor(lpart[f], 32);
        float inv = 1.0f / lrow;
        char* slot = (char*)ldsbuf + w * 8192 + f * 4096 + l * 64;
        #pragma unroll
        for (int j = 0; j < 4; ++j) {
            int df = j >> 1, r0 = (j & 1) * 8;
            uint4 u;
            u.x = pk_f16(yacc[f][df][r0 + 0] * inv, yacc[f][df][r0 + 1] * inv);
            u.y = pk_f16(yacc[f][df][r0 + 2] * inv, yacc[f][df][r0 + 3] * inv);
            u.z = pk_f16(yacc[f][df][r0 + 4] * inv, yacc[f][df][r0 + 5] * inv);
            u.w = pk_f16(yacc[f][df][r0 + 6] * inv, yacc[f][df][r0 + 7] * inv);
            *(uint4*)(slot + (j * 16 ^ ((l & 3) << 4))) = u;
        }
        zf[(w * 2 + f) * 32 + q32] = mrow[f] + __log2f(lrow);
    }
    __syncthreads();
    if (w >= 2) return;

    // ---- combine 4 kh partials per f (slots kp*2 + w; this wave: qp = w)
    #pragma unroll
    for (int f = 0; f < 2; ++f) {
        float zq[4];
        #pragma unroll
        for (int kp = 0; kp < 4; ++kp)
            zq[kp] = zf[((kp * 2 + w) * 2 + f) * 32 + q32];
        float zmx = fmaxf(fmaxf(zq[0], zq[1]), fmaxf(zq[2], zq[3]));
        float wsum = 0.f;
        float yfin[2][16];
        #pragma unroll
        for (int df = 0; df < 2; ++df)
            #pragma unroll
            for (int r = 0; r < 16; ++r) yfin[df][r] = 0.f;
        #pragma unroll
        for (int kp = 0; kp < 4; ++kp) {
            char* slot = (char*)ldsbuf + (kp * 2 + w) * 8192 + f * 4096 + l * 64;
            float wk = fexp2(zq[kp] - zmx);
            wsum += wk;
            #pragma unroll
            for (int j = 0; j < 4; ++j) {
                v8h c = *(const v8h*)(slot + (j * 16 ^ ((l & 3) << 4)));
                int df = j >> 1, r0 = (j & 1) * 8;
                #pragma unroll
                for (int e = 0; e < 8; ++e)
                    yfin[df][r0 + e] += wk * (float)c[e];
            }
        }
        float nrm = 1.0f / wsum;
        // epilogue A-frags: y rows q, k = d
        v8h yA[4];
        #pragma unroll
        for (int kc = 0; kc < 4; ++kc) {
            int df = kc >> 1, r0 = (kc & 1) * 8;
            unsigned int Wa = pk_f16(yfin[df][r0 + 0] * nrm, yfin[df][r0 + 1] * nrm);
            unsigned int Wb2 = pk_f16(yfin[df][r0 + 2] * nrm, yfin[df][r0 + 3] * nrm);
            unsigned int Wc = pk_f16(yfin[df][r0 + 4] * nrm, yfin[df][r0 + 5] * nrm);
            unsigned int Wd = pk_f16(yfin[df][r0 + 6] * nrm, yfin[df][r0 + 7] * nrm);
            pl32swap(Wa, Wc); pl32swap(Wb2, Wd);
            uint4 u; u.x = Wa; u.y = Wb2; u.z = Wc; u.w = Wd;
            yA[kc] = __builtin_bit_cast(v8h, u);
        }
        // wy = y @ W -> BN + residual; queries qb*128 + w*64 + f*32 + qrow
        const int tokA = qb * 128 + w * 64 + f * 32;
        const float* xb = x + (size_t)b * 4096 * 128;
        float* ob = out + (size_t)b * 4096 * 128;
        #pragma unroll
        for (int cf = 0; cf < 4; ++cf) {
            int c = cf * 32 + q32;
            v16f wy;
            #pragma unroll
            for (int r = 0; r < 16; ++r) wy[r] = 0.f;
            #pragma unroll
            for (int kc = 0; kc < 4; ++kc) {
                v8h wB = *(const v8h*)(Wt + c * 64 + kc * 16 + hi2 * 8);
                wy = MFMA32(yA[kc], wB, wy);
            }
            float scc = sc[c], bic = bi[c];
            #pragma unroll
            for (int r = 0; r < 16; ++r) {
                int qrow = (r & 3) + 8 * (r >> 2) + 4 * hi2;
                size_t off = (size_t)(tokA + qrow) * 128 + c;
                ob[off] = wy[r] * scc + bic + xb[off];
            }
        }
    }
}

// ------------------------------------------------------------------ launch --
extern "C" void kernel_launch(void* const* d_in, const int* in_sizes, int n_in,
                              void* d_out, int out_size, void* d_ws, size_t ws_size,
                              hipStream_t stream) {
    const float* x     = (const float*)d_in[0];
    const float* tw    = (const float*)d_in[1];
    const float* tb    = (const float*)d_in[2];
    const float* pw    = (const float*)d_in[3];
    const float* pb    = (const float*)d_in[4];
    const float* gw    = (const float*)d_in[5];
    const float* gb    = (const float*)d_in[6];
    const float* Ww    = (const float*)d_in[7];
    const float* Wb    = (const float*)d_in[8];
    const float* gamma = (const float*)d_in[9];
    const float* beta  = (const float*)d_in[10];
    const float* mean  = (const float*)d_in[11];
    const float* var   = (const float*)d_in[12];

    char* ws = (char*)d_ws;
    _Float16* theta = (_Float16*)ws;                       // 4 MB (log2-scaled)
    _Float16* phi   = (_Float16*)(ws + (4u << 20));        // 4 MB
    _Float16* gT    = (_Float16*)(ws + (8u << 20));        // 4 MB
    _Float16* Wt    = (_Float16*)(ws + (12u << 20));       // 16 KB
    _Float16* wallT = (_Float16*)(ws + (12u << 20) + (1u << 16));  // 48 KB
    float* sc       = (float*)(ws + (12u << 20) + (2u << 16));
    float* bi       = sc + 128;

    k_prep<<<16, 256, 0, stream>>>(tw, pw, gw, Ww, Wb, gamma, beta, mean, var,
                                   Wt, wallT, sc, bi);
    k_proj<<<256, 512, 0, stream>>>(x, wallT, tb, pb, gb, theta, phi, gT);
    k_attn<<<256, 512, 0, stream>>>(theta, phi, gT, Wt, sc, bi,
                                    x, (float*)d_out);
}